// Round 1
// baseline (511.181 us; speedup 1.0000x reference)
//
#include <hip/hip_runtime.h>
#include <hip/hip_bf16.h>

#define NHEAD 4
#define DSIZE 32
#define DIN 128
#define DOUT 128

// ---------------- K1: fused dual projection + ReLU + attention logits ----------------
// 512 threads: channel c = t&255 (c<128 -> W0/h_self, c>=128 -> W1/h_neigh),
// subgroup s = t>>8 handles 8 nodes each; 16 nodes per chunk.
#define K1_THREADS 512
#define K1_NPS 8
#define K1_NCHUNK 16
#define W_PITCH 132   // 128 + 4 floats: keeps float4 LDS reads at minimum bank cost

__global__ __launch_bounds__(K1_THREADS) void k1_proj(
    const float* __restrict__ feat, const float* __restrict__ W0,
    const float* __restrict__ b0, const float* __restrict__ W1,
    const float* __restrict__ b1, const float* __restrict__ att,
    float* __restrict__ h_self, float* __restrict__ h_neigh,
    float* __restrict__ att_self, float* __restrict__ att_neigh,
    int n_nodes)
{
    __shared__ float Wl[256 * W_PITCH];      // 135168 B
    __shared__ float Xl[K1_NCHUNK * DIN];    // 8192 B
    const int t = threadIdx.x;

    // stage both weight matrices into LDS
    for (int idx = t; idx < 256 * DIN; idx += K1_THREADS) {
        int c = idx >> 7, k = idx & 127;
        float v = (c < 128) ? W0[c * DIN + k] : W1[(c - 128) * DIN + k];
        Wl[c * W_PITCH + k] = v;
    }

    const int c = t & 255;
    const int s = t >> 8;
    const float bias = (c < 128) ? b0[c] : b1[c - 128];
    const float aw = att[c];  // attention flat [2][4][32] == one per channel c
    float* const hout = (c < 128) ? h_self : h_neigh;
    float* const aout = (c < 128) ? att_self : att_neigh;
    const int ch = c & 127;

    const int nchunks = (n_nodes + K1_NCHUNK - 1) / K1_NCHUNK;
    for (int chunk = blockIdx.x; chunk < nchunks; chunk += gridDim.x) {
        const int base = chunk * K1_NCHUNK;
        __syncthreads();
        {   // stage 16 node rows (one float4 per thread)
            int r = t >> 5, q = t & 31;
            int node = base + r;
            float4 v = make_float4(0.f, 0.f, 0.f, 0.f);
            if (node < n_nodes) v = *(const float4*)(feat + (size_t)node * DIN + q * 4);
            *(float4*)(Xl + r * DIN + q * 4) = v;
        }
        __syncthreads();

        float acc[K1_NPS];
        #pragma unroll
        for (int i = 0; i < K1_NPS; i++) acc[i] = 0.f;
        const float* Wrow = Wl + c * W_PITCH;
        const float* Xb   = Xl + s * K1_NPS * DIN;
        #pragma unroll 4
        for (int k = 0; k < DIN; k += 4) {
            float4 w = *(const float4*)(Wrow + k);
            #pragma unroll
            for (int i = 0; i < K1_NPS; i++) {
                float4 x = *(const float4*)(Xb + i * DIN + k);
                acc[i] = fmaf(w.x, x.x, acc[i]);
                acc[i] = fmaf(w.y, x.y, acc[i]);
                acc[i] = fmaf(w.z, x.z, acc[i]);
                acc[i] = fmaf(w.w, x.w, acc[i]);
            }
        }

        #pragma unroll
        for (int i = 0; i < K1_NPS; i++) {
            int node = base + s * K1_NPS + i;
            float v = acc[i] + bias;
            v = v > 0.f ? v : 0.f;                       // ReLU
            if (node < n_nodes) hout[(size_t)node * DOUT + ch] = v;
            // attention logit: reduce v*aw over the 32 lanes of this head
            float contrib = v * aw;
            contrib += __shfl_xor(contrib, 1);
            contrib += __shfl_xor(contrib, 2);
            contrib += __shfl_xor(contrib, 4);
            contrib += __shfl_xor(contrib, 8);
            contrib += __shfl_xor(contrib, 16);
            float l = contrib > 0.f ? contrib : 0.2f * contrib;  // leaky relu
            if ((ch & 31) == 0 && node < n_nodes)
                aout[(size_t)node * NHEAD + (ch >> 5)] = l;
        }
    }
}

// ---------------- K2: CSR offsets by binary search on sorted edge_row ----------------
__global__ void k2_rowptr(const int* __restrict__ erow, int* __restrict__ rowptr,
                          int n_nodes, int nedge)
{
    int n = blockIdx.x * blockDim.x + threadIdx.x;
    if (n > n_nodes) return;
    int lo = 0, hi = nedge;
    while (lo < hi) { int mid = (lo + hi) >> 1; if (erow[mid] < n) lo = mid + 1; else hi = mid; }
    rowptr[n] = lo;
}

// ---------------- K3: segment softmax + weighted aggregate + dual layernorm ----------------
__device__ __forceinline__ float group32_sum(float v) {
    v += __shfl_xor(v, 1);
    v += __shfl_xor(v, 2);
    v += __shfl_xor(v, 4);
    v += __shfl_xor(v, 8);
    v += __shfl_xor(v, 16);
    return v;
}

__global__ __launch_bounds__(128) void k3_agg(
    const int* __restrict__ rowptr, const int* __restrict__ ecol,
    const float* __restrict__ eval,
    const float* __restrict__ att_self, const float* __restrict__ att_neigh,
    const float* __restrict__ h_self, const float* __restrict__ h_neigh,
    const float* __restrict__ scale, const float* __restrict__ offset,
    float* __restrict__ out, int n_nodes)
{
    const int n = blockIdx.x;
    const int t = threadIdx.x;       // 0..127 -> channel
    const int h = t >> 5;            // head
    const int wave = t >> 6;         // 0..1
    const int start = rowptr[n], end = rowptr[n + 1];

    __shared__ float wred[2][NHEAD];

    const float4 a4 = *(const float4*)(att_self + (size_t)n * NHEAD);
    const float as[NHEAD] = {a4.x, a4.y, a4.z, a4.w};

    // phase 1: per-head max over this node's edges (edge-parallel)
    float lmax[NHEAD] = {-1e30f, -1e30f, -1e30f, -1e30f};
    for (int e = start + t; e < end; e += 128) {
        int col = ecol[e];
        float4 an = *(const float4*)(att_neigh + (size_t)col * NHEAD);
        lmax[0] = fmaxf(lmax[0], as[0] + an.x);
        lmax[1] = fmaxf(lmax[1], as[1] + an.y);
        lmax[2] = fmaxf(lmax[2], as[2] + an.z);
        lmax[3] = fmaxf(lmax[3], as[3] + an.w);
    }
    #pragma unroll
    for (int i = 0; i < NHEAD; i++) {
        float v = lmax[i];
        v = fmaxf(v, __shfl_xor(v, 1));
        v = fmaxf(v, __shfl_xor(v, 2));
        v = fmaxf(v, __shfl_xor(v, 4));
        v = fmaxf(v, __shfl_xor(v, 8));
        v = fmaxf(v, __shfl_xor(v, 16));
        v = fmaxf(v, __shfl_xor(v, 32));
        lmax[i] = v;
    }
    if ((t & 63) == 0) {
        #pragma unroll
        for (int i = 0; i < NHEAD; i++) wred[wave][i] = lmax[i];
    }
    __syncthreads();
    const float mx = fmaxf(wred[0][h], wred[1][h]);
    const float ash = as[h];

    // phase 2: all threads walk the segment; thread owns channel t
    float acc = 0.f, sumw = 0.f;
    for (int e = start; e < end; e++) {
        int col = ecol[e];
        float an = att_neigh[(size_t)col * NHEAD + h];
        float w = expf(ash + an - mx) * eval[e];
        sumw += w;
        acc = fmaf(w, h_neigh[(size_t)col * DOUT + t], acc);
    }
    float denom = fmaxf(sumw, 1e-10f);
    float agg = acc / denom;

    // per-head layernorm (two-pass) of agg (params b=0) and h_self (params b=1)
    float m0 = group32_sum(agg) * (1.f / 32.f);
    float d0 = agg - m0;
    float v0 = group32_sum(d0 * d0) * (1.f / 32.f);
    float nn = d0 * scale[t] * rsqrtf(v0 + 1e-9f) + offset[t];

    float hs = h_self[(size_t)n * DOUT + t];
    float m1 = group32_sum(hs) * (1.f / 32.f);
    float d1 = hs - m1;
    float v1 = group32_sum(d1 * d1) * (1.f / 32.f);
    float ns = d1 * scale[128 + t] * rsqrtf(v1 + 1e-9f) + offset[128 + t];

    out[(size_t)n * DOUT + t] = 0.5f * (ns + nn);
}

extern "C" void kernel_launch(void* const* d_in, const int* in_sizes, int n_in,
                              void* d_out, int out_size, void* d_ws, size_t ws_size,
                              hipStream_t stream) {
    const float* feat  = (const float*)d_in[0];
    const int*   erow  = (const int*)  d_in[1];
    const int*   ecol  = (const int*)  d_in[2];
    const float* eval  = (const float*)d_in[3];
    const float* W0    = (const float*)d_in[4];
    const float* b0    = (const float*)d_in[5];
    const float* W1    = (const float*)d_in[6];
    const float* b1    = (const float*)d_in[7];
    const float* att   = (const float*)d_in[8];
    const float* scale = (const float*)d_in[9];
    const float* offs  = (const float*)d_in[10];
    const int n = in_sizes[0] / DIN;
    const int E = in_sizes[2];

    float* h_self    = (float*)d_ws;
    float* h_neigh   = h_self  + (size_t)n * DOUT;
    float* att_self  = h_neigh + (size_t)n * DOUT;
    float* att_neigh = att_self + (size_t)n * NHEAD;
    int*   rowptr    = (int*)(att_neigh + (size_t)n * NHEAD);

    k1_proj<<<2048, K1_THREADS, 0, stream>>>(feat, W0, b0, W1, b1, att,
                                             h_self, h_neigh, att_self, att_neigh, n);
    k2_rowptr<<<(n + 1 + 255) / 256, 256, 0, stream>>>(erow, rowptr, n, E);
    k3_agg<<<n, 128, 0, stream>>>(rowptr, ecol, eval, att_self, att_neigh,
                                  h_self, h_neigh, scale, offs, (float*)d_out, n);
}

// Round 2
// 294.674 us; speedup vs baseline: 1.7347x; 1.7347x over previous
//
#include <hip/hip_runtime.h>
#include <hip/hip_bf16.h>

#define NHEAD 4
#define DIN 128
#define DOUT 128

typedef __attribute__((ext_vector_type(8))) short bf16x8;
typedef __attribute__((ext_vector_type(4))) float f32x4;

__device__ __forceinline__ short bfb(float f) {
    __hip_bfloat16 h = __float2bfloat16(f);
    return *reinterpret_cast<short*>(&h);
}

__device__ __forceinline__ bf16x8 cvt8(const float* __restrict__ p) {
    float4 u = *(const float4*)p;
    float4 v = *(const float4*)(p + 4);
    bf16x8 r;
    r[0] = bfb(u.x); r[1] = bfb(u.y); r[2] = bfb(u.z); r[3] = bfb(u.w);
    r[4] = bfb(v.x); r[5] = bfb(v.y); r[6] = bfb(v.z); r[7] = bfb(v.w);
    return r;
}

// ---------------- K1: MFMA dual projection + ReLU + attention logits ----------------
// 256 threads = 4 waves. Wave w owns channels [w*64, w*64+64): w<2 -> h_self (W0),
// w>=2 -> h_neigh (W1). Weights held in VGPRs (bf16), 16-node tiles, 8 tiles/block.
#define NPB 128   // nodes per block

__global__ __launch_bounds__(256) void k1_mfma(
    const float* __restrict__ feat, const float* __restrict__ W0,
    const float* __restrict__ b0, const float* __restrict__ W1,
    const float* __restrict__ b1, const float* __restrict__ att,
    float* __restrict__ h_self, float* __restrict__ h_neigh,
    float* __restrict__ att_self, float* __restrict__ att_neigh,
    int n)
{
    const int t = threadIdx.x;
    const int w = t >> 6;          // wave 0..3
    const int lane = t & 63;
    const int col = lane & 15;     // channel-within-16 (and A row index)
    const int rg = lane >> 4;      // k-group / row-group
    __shared__ float attbuf[16][8];

    // preload B fragments (weights) for this wave's 64 channels, bf16 in regs
    bf16x8 bw[4][4];
    float bias[4], aw[4];
    #pragma unroll
    for (int ct = 0; ct < 4; ct++) {
        int ch = w * 64 + ct * 16 + col;          // global channel 0..255
        int chm = ch & 127;
        const float* wrow = (ch < 128 ? W0 : W1) + (size_t)chm * DIN;
        #pragma unroll
        for (int kk = 0; kk < 4; kk++)
            bw[ct][kk] = cvt8(wrow + kk * 32 + rg * 8);
        bias[ct] = (ch < 128 ? b0 : b1)[chm];
        aw[ct]   = att[ch];
    }
    float* const hout = (w < 2) ? h_self : h_neigh;

    const int ntiles = (n + 15) >> 4;
    const int tile0 = blockIdx.x * (NPB / 16);
    const int tile1 = min(tile0 + NPB / 16, ntiles);

    for (int tile = tile0; tile < tile1; tile++) {
        const int base = tile * 16;
        const int anode = base + col;
        const bool avalid = anode < n;
        const float* arow = feat + (size_t)anode * DIN + rg * 8;

        bf16x8 a[4];
        if (avalid) {
            #pragma unroll
            for (int kk = 0; kk < 4; kk++) a[kk] = cvt8(arow + kk * 32);
        } else {
            #pragma unroll
            for (int kk = 0; kk < 4; kk++) {
                #pragma unroll
                for (int i = 0; i < 8; i++) a[kk][i] = 0;
            }
        }

        f32x4 acc[4] = {{0.f,0.f,0.f,0.f},{0.f,0.f,0.f,0.f},
                        {0.f,0.f,0.f,0.f},{0.f,0.f,0.f,0.f}};
        #pragma unroll
        for (int kk = 0; kk < 4; kk++) {
            #pragma unroll
            for (int ct = 0; ct < 4; ct++)
                acc[ct] = __builtin_amdgcn_mfma_f32_16x16x32_bf16(
                              a[kk], bw[ct][kk], acc[ct], 0, 0, 0);
        }

        __syncthreads();   // attbuf from previous tile fully consumed

        // epilogue: bias + ReLU + store h; accumulate attention partials
        float vv[4][4];
        #pragma unroll
        for (int ct = 0; ct < 4; ct++) {
            #pragma unroll
            for (int j = 0; j < 4; j++) {
                float v = acc[ct][j] + bias[ct];
                v = v > 0.f ? v : 0.f;
                vv[ct][j] = v;
                int node = base + rg * 4 + j;
                int chm = (w * 64 + ct * 16 + col) & 127;
                if (node < n) hout[(size_t)node * DOUT + chm] = v;
            }
        }
        // attention logits: p0 sums channels [w*64, w*64+32), p1 the next 32.
        #pragma unroll
        for (int j = 0; j < 4; j++) {
            float p0 = vv[0][j] * aw[0] + vv[1][j] * aw[1];
            float p1 = vv[2][j] * aw[2] + vv[3][j] * aw[3];
            #pragma unroll
            for (int m = 1; m < 16; m <<= 1) {
                p0 += __shfl_xor(p0, m);
                p1 += __shfl_xor(p1, m);
            }
            if (col == 0) {
                attbuf[rg * 4 + j][w * 2]     = p0;  // slot = self/neigh-major head
                attbuf[rg * 4 + j][w * 2 + 1] = p1;
            }
        }
        __syncthreads();
        if (t < 128) {
            int r = t >> 3, s = t & 7;
            int node = base + r;
            if (node < n) {
                float v = attbuf[r][s];
                v = v > 0.f ? v : 0.2f * v;            // leaky relu
                ((s < 4) ? att_self : att_neigh)[(size_t)node * NHEAD + (s & 3)] = v;
            }
        }
    }
}

// ---------------- K2: CSR offsets by binary search on sorted edge_row ----------------
__global__ void k2_rowptr(const int* __restrict__ erow, int* __restrict__ rowptr,
                          int n_nodes, int nedge)
{
    int n = blockIdx.x * blockDim.x + threadIdx.x;
    if (n > n_nodes) return;
    int lo = 0, hi = nedge;
    while (lo < hi) { int mid = (lo + hi) >> 1; if (erow[mid] < n) lo = mid + 1; else hi = mid; }
    rowptr[n] = lo;
}

// ---------------- K2b: per-edge softmax numerators (no max; logits are tiny) --------
__global__ __launch_bounds__(256) void k_edgew(
    const int* __restrict__ erow, const int* __restrict__ ecol,
    const float* __restrict__ eval,
    const float* __restrict__ att_self, const float* __restrict__ att_neigh,
    float* __restrict__ wbuf, int E)
{
    int e = blockIdx.x * blockDim.x + threadIdx.x;
    if (e >= E) return;
    int r = erow[e], c = ecol[e];
    float4 s  = *(const float4*)(att_self  + (size_t)r * NHEAD);
    float4 nb = *(const float4*)(att_neigh + (size_t)c * NHEAD);
    float ev = eval[e];
    float4 wv;
    wv.x = __expf(s.x + nb.x) * ev;
    wv.y = __expf(s.y + nb.y) * ev;
    wv.z = __expf(s.z + nb.z) * ev;
    wv.w = __expf(s.w + nb.w) * ev;
    *(float4*)(wbuf + (size_t)e * NHEAD) = wv;
}

// ---------------- K3: weighted aggregate + dual per-head layernorm ----------------
__device__ __forceinline__ float group32_sum(float v) {
    v += __shfl_xor(v, 1);
    v += __shfl_xor(v, 2);
    v += __shfl_xor(v, 4);
    v += __shfl_xor(v, 8);
    v += __shfl_xor(v, 16);
    return v;
}

__global__ __launch_bounds__(128) void k3_agg(
    const int* __restrict__ rowptr, const int* __restrict__ ecol,
    const float* __restrict__ wbuf,
    const float* __restrict__ h_self, const float* __restrict__ h_neigh,
    const float* __restrict__ scale, const float* __restrict__ offset,
    float* __restrict__ out, int n_nodes)
{
    const int nid = blockIdx.x;
    const int t = threadIdx.x;       // channel 0..127
    const int h = t >> 5;            // head
    const int start = rowptr[nid], end = rowptr[nid + 1];

    float acc = 0.f, sumw = 0.f;
    int e = start;
    int col = (e < end) ? ecol[e] : 0;
    for (; e < end; e++) {
        int ncol = (e + 1 < end) ? ecol[e + 1] : 0;
        float wh = wbuf[(size_t)e * NHEAD + h];
        float hv = h_neigh[(size_t)col * DOUT + t];
        sumw += wh;
        acc = fmaf(wh, hv, acc);
        col = ncol;
    }
    float denom = fmaxf(sumw, 1e-10f);
    float agg = acc / denom;

    // per-head layernorm (two-pass) of agg (params b=0) and h_self (params b=1)
    float m0 = group32_sum(agg) * (1.f / 32.f);
    float d0 = agg - m0;
    float v0 = group32_sum(d0 * d0) * (1.f / 32.f);
    float nn = d0 * scale[t] * rsqrtf(v0 + 1e-9f) + offset[t];

    float hs = h_self[(size_t)nid * DOUT + t];
    float m1 = group32_sum(hs) * (1.f / 32.f);
    float d1 = hs - m1;
    float v1 = group32_sum(d1 * d1) * (1.f / 32.f);
    float ns = d1 * scale[128 + t] * rsqrtf(v1 + 1e-9f) + offset[128 + t];

    out[(size_t)nid * DOUT + t] = 0.5f * (ns + nn);
}

extern "C" void kernel_launch(void* const* d_in, const int* in_sizes, int n_in,
                              void* d_out, int out_size, void* d_ws, size_t ws_size,
                              hipStream_t stream) {
    const float* feat  = (const float*)d_in[0];
    const int*   erow  = (const int*)  d_in[1];
    const int*   ecol  = (const int*)  d_in[2];
    const float* eval  = (const float*)d_in[3];
    const float* W0    = (const float*)d_in[4];
    const float* b0    = (const float*)d_in[5];
    const float* W1    = (const float*)d_in[6];
    const float* b1    = (const float*)d_in[7];
    const float* att   = (const float*)d_in[8];
    const float* scale = (const float*)d_in[9];
    const float* offs  = (const float*)d_in[10];
    const int n = in_sizes[0] / DIN;
    const int E = in_sizes[2];

    float* h_self    = (float*)d_ws;
    float* h_neigh   = h_self    + (size_t)n * DOUT;
    float* att_self  = h_neigh   + (size_t)n * DOUT;
    float* att_neigh = att_self  + (size_t)n * NHEAD;
    float* wbuf      = att_neigh + (size_t)n * NHEAD;          // 16B-aligned
    int*   rowptr    = (int*)(wbuf + (size_t)E * NHEAD);

    k1_mfma<<<(n + NPB - 1) / NPB, 256, 0, stream>>>(
        feat, W0, b0, W1, b1, att, h_self, h_neigh, att_self, att_neigh, n);
    k2_rowptr<<<(n + 1 + 255) / 256, 256, 0, stream>>>(erow, rowptr, n, E);
    k_edgew<<<(E + 255) / 256, 256, 0, stream>>>(erow, ecol, eval,
                                                 att_self, att_neigh, wbuf, E);
    k3_agg<<<n, 128, 0, stream>>>(rowptr, ecol, wbuf, h_self, h_neigh,
                                  scale, offs, (float*)d_out, n);
}

// Round 3
// 168.143 us; speedup vs baseline: 3.0402x; 1.7525x over previous
//
#include <hip/hip_runtime.h>
#include <hip/hip_bf16.h>

#define NHEAD 4
#define DIN 128
#define DOUT 128

typedef __attribute__((ext_vector_type(8))) short bf16x8;
typedef __attribute__((ext_vector_type(4))) float f32x4;

__device__ __forceinline__ short bfb(float f) {
    __hip_bfloat16 h = __float2bfloat16(f);
    return *reinterpret_cast<short*>(&h);
}

__device__ __forceinline__ float bf2f(unsigned short u) {
    unsigned int x = ((unsigned int)u) << 16;
    return __uint_as_float(x);
}

__device__ __forceinline__ bf16x8 cvt8(const float* __restrict__ p) {
    float4 u = *(const float4*)p;
    float4 v = *(const float4*)(p + 4);
    bf16x8 r;
    r[0] = bfb(u.x); r[1] = bfb(u.y); r[2] = bfb(u.z); r[3] = bfb(u.w);
    r[4] = bfb(v.x); r[5] = bfb(v.y); r[6] = bfb(v.z); r[7] = bfb(v.w);
    return r;
}

// ---------------- K1: MFMA dual projection + ReLU + attention logits ----------------
// 256 threads = 4 waves. Wave w owns channels [w*64, w*64+64): w<2 -> h_self (f32),
// w>=2 -> h_neigh (bf16). Weights held in VGPRs (bf16), 16-node tiles.
#define NPB 128   // nodes per block

__global__ __launch_bounds__(256) void k1_mfma(
    const float* __restrict__ feat, const float* __restrict__ W0,
    const float* __restrict__ b0, const float* __restrict__ W1,
    const float* __restrict__ b1, const float* __restrict__ att,
    float* __restrict__ h_self, unsigned short* __restrict__ h_neigh,
    float* __restrict__ att_self, float* __restrict__ att_neigh,
    int n)
{
    const int t = threadIdx.x;
    const int w = t >> 6;          // wave 0..3
    const int lane = t & 63;
    const int col = lane & 15;     // channel-within-16 (and A row index)
    const int rg = lane >> 4;      // k-group / row-group
    __shared__ float attbuf[16][8];

    // preload B fragments (weights) for this wave's 64 channels, bf16 in regs
    bf16x8 bw[4][4];
    float bias[4], aw[4];
    #pragma unroll
    for (int ct = 0; ct < 4; ct++) {
        int ch = w * 64 + ct * 16 + col;          // global channel 0..255
        int chm = ch & 127;
        const float* wrow = (ch < 128 ? W0 : W1) + (size_t)chm * DIN;
        #pragma unroll
        for (int kk = 0; kk < 4; kk++)
            bw[ct][kk] = cvt8(wrow + kk * 32 + rg * 8);
        bias[ct] = (ch < 128 ? b0 : b1)[chm];
        aw[ct]   = att[ch];
    }

    const int ntiles = (n + 15) >> 4;
    const int tile0 = blockIdx.x * (NPB / 16);
    const int tile1 = min(tile0 + NPB / 16, ntiles);

    for (int tile = tile0; tile < tile1; tile++) {
        const int base = tile * 16;
        const int anode = base + col;
        const bool avalid = anode < n;
        const float* arow = feat + (size_t)anode * DIN + rg * 8;

        bf16x8 a[4];
        if (avalid) {
            #pragma unroll
            for (int kk = 0; kk < 4; kk++) a[kk] = cvt8(arow + kk * 32);
        } else {
            #pragma unroll
            for (int kk = 0; kk < 4; kk++) {
                #pragma unroll
                for (int i = 0; i < 8; i++) a[kk][i] = 0;
            }
        }

        f32x4 acc[4] = {{0.f,0.f,0.f,0.f},{0.f,0.f,0.f,0.f},
                        {0.f,0.f,0.f,0.f},{0.f,0.f,0.f,0.f}};
        #pragma unroll
        for (int kk = 0; kk < 4; kk++) {
            #pragma unroll
            for (int ct = 0; ct < 4; ct++)
                acc[ct] = __builtin_amdgcn_mfma_f32_16x16x32_bf16(
                              a[kk], bw[ct][kk], acc[ct], 0, 0, 0);
        }

        __syncthreads();   // attbuf from previous tile fully consumed

        // epilogue: bias + ReLU + store h; accumulate attention partials
        float vv[4][4];
        #pragma unroll
        for (int ct = 0; ct < 4; ct++) {
            #pragma unroll
            for (int j = 0; j < 4; j++) {
                float v = acc[ct][j] + bias[ct];
                v = v > 0.f ? v : 0.f;
                vv[ct][j] = v;
                int node = base + rg * 4 + j;
                int chm = (w * 64 + ct * 16 + col) & 127;
                if (node < n) {
                    if (w < 2) h_self[(size_t)node * DOUT + chm] = v;
                    else       h_neigh[(size_t)node * DOUT + chm] = (unsigned short)bfb(v);
                }
            }
        }
        // attention logits: p0 sums channels [w*64, w*64+32), p1 the next 32.
        #pragma unroll
        for (int j = 0; j < 4; j++) {
            float p0 = vv[0][j] * aw[0] + vv[1][j] * aw[1];
            float p1 = vv[2][j] * aw[2] + vv[3][j] * aw[3];
            #pragma unroll
            for (int m = 1; m < 16; m <<= 1) {
                p0 += __shfl_xor(p0, m);
                p1 += __shfl_xor(p1, m);
            }
            if (col == 0) {
                attbuf[rg * 4 + j][w * 2]     = p0;
                attbuf[rg * 4 + j][w * 2 + 1] = p1;
            }
        }
        __syncthreads();
        if (t < 128) {
            int r = t >> 3, s = t & 7;
            int node = base + r;
            if (node < n) {
                float v = attbuf[r][s];
                v = v > 0.f ? v : 0.2f * v;            // leaky relu
                ((s < 4) ? att_self : att_neigh)[(size_t)node * NHEAD + (s & 3)] = v;
            }
        }
    }
}

// ---------------- K2: CSR offsets by binary search on sorted edge_row ----------------
__global__ void k2_rowptr(const int* __restrict__ erow, int* __restrict__ rowptr,
                          int n_nodes, int nedge)
{
    int n = blockIdx.x * blockDim.x + threadIdx.x;
    if (n > n_nodes) return;
    int lo = 0, hi = nedge;
    while (lo < hi) { int mid = (lo + hi) >> 1; if (erow[mid] < n) lo = mid + 1; else hi = mid; }
    rowptr[n] = lo;
}

// ---------------- K2b: per-edge softmax numerators (no max; logits are small) -------
__global__ __launch_bounds__(256) void k_edgew(
    const int* __restrict__ erow, const int* __restrict__ ecol,
    const float* __restrict__ eval,
    const float* __restrict__ att_self, const float* __restrict__ att_neigh,
    float* __restrict__ wbuf, int E)
{
    int e = blockIdx.x * blockDim.x + threadIdx.x;
    if (e >= E) return;
    int r = erow[e], c = ecol[e];
    float4 s  = *(const float4*)(att_self  + (size_t)r * NHEAD);
    float4 nb = *(const float4*)(att_neigh + (size_t)c * NHEAD);
    float ev = eval[e];
    float4 wv;
    wv.x = __expf(s.x + nb.x) * ev;
    wv.y = __expf(s.y + nb.y) * ev;
    wv.z = __expf(s.z + nb.z) * ev;
    wv.w = __expf(s.w + nb.w) * ev;
    *(float4*)(wbuf + (size_t)e * NHEAD) = wv;
}

// ---------------- K3: weighted aggregate + dual per-head layernorm ----------------
// 256 threads = 8 nodes/block, 32 lanes/node, 4 channels/thread (float4-wide gather).
// Edge loop in pipelined batches of 4 (next batch's cols prefetched).
__device__ __forceinline__ float group8_sum(float v) {
    v += __shfl_xor(v, 1);
    v += __shfl_xor(v, 2);
    v += __shfl_xor(v, 4);
    return v;
}

__global__ __launch_bounds__(256) void k3_agg(
    const int* __restrict__ rowptr, const int* __restrict__ ecol,
    const float* __restrict__ wbuf,
    const float* __restrict__ h_self, const unsigned short* __restrict__ h_neigh,
    const float* __restrict__ scale, const float* __restrict__ offset,
    float* __restrict__ out, int n_nodes)
{
    const int t = threadIdx.x;
    const int g = t >> 5;                       // node slot in block
    const int lane = t & 31;
    const int nid = blockIdx.x * 8 + g;
    if (nid >= n_nodes) return;
    const int h = lane >> 3;                    // head
    const int c4 = lane * 4;                    // first of 4 owned channels

    const int start = rowptr[nid], end = rowptr[nid + 1];

    float acc0 = 0.f, acc1 = 0.f, acc2 = 0.f, acc3 = 0.f, sumw = 0.f;

    int cols[4];
    #pragma unroll
    for (int i = 0; i < 4; i++) {
        int e = start + i;
        cols[i] = (e < end) ? ecol[e] : 0;
    }

    for (int e = start; e < end; e += 4) {
        float wh[4];
        ushort4 hv[4];
        #pragma unroll
        for (int i = 0; i < 4; i++) {
            bool valid = (e + i) < end;
            wh[i] = valid ? wbuf[(size_t)(e + i) * NHEAD + h] : 0.f;
            hv[i] = *(const ushort4*)(h_neigh + (size_t)cols[i] * DOUT + c4);
        }
        int ncols[4];
        #pragma unroll
        for (int i = 0; i < 4; i++) {
            int en = e + 4 + i;
            ncols[i] = (en < end) ? ecol[en] : 0;
        }
        #pragma unroll
        for (int i = 0; i < 4; i++) {
            sumw += wh[i];
            acc0 = fmaf(wh[i], bf2f(hv[i].x), acc0);
            acc1 = fmaf(wh[i], bf2f(hv[i].y), acc1);
            acc2 = fmaf(wh[i], bf2f(hv[i].z), acc2);
            acc3 = fmaf(wh[i], bf2f(hv[i].w), acc3);
        }
        #pragma unroll
        for (int i = 0; i < 4; i++) cols[i] = ncols[i];
    }

    const float rden = 1.f / fmaxf(sumw, 1e-10f);
    float a0 = acc0 * rden, a1 = acc1 * rden, a2 = acc2 * rden, a3 = acc3 * rden;

    // layernorm of agg over this head's 32 channels (8 lanes x 4)
    float m0 = group8_sum(a0 + a1 + a2 + a3) * (1.f / 32.f);
    float d0 = a0 - m0, d1 = a1 - m0, d2 = a2 - m0, d3 = a3 - m0;
    float v0 = group8_sum(d0*d0 + d1*d1 + d2*d2 + d3*d3) * (1.f / 32.f);
    float r0 = rsqrtf(v0 + 1e-9f);
    float4 sc0 = *(const float4*)(scale + c4);
    float4 of0 = *(const float4*)(offset + c4);
    float nn0 = d0 * sc0.x * r0 + of0.x;
    float nn1 = d1 * sc0.y * r0 + of0.y;
    float nn2 = d2 * sc0.z * r0 + of0.z;
    float nn3 = d3 * sc0.w * r0 + of0.w;

    // layernorm of h_self
    float4 hs = *(const float4*)(h_self + (size_t)nid * DOUT + c4);
    float m1 = group8_sum(hs.x + hs.y + hs.z + hs.w) * (1.f / 32.f);
    float e0 = hs.x - m1, e1 = hs.y - m1, e2 = hs.z - m1, e3 = hs.w - m1;
    float v1 = group8_sum(e0*e0 + e1*e1 + e2*e2 + e3*e3) * (1.f / 32.f);
    float r1 = rsqrtf(v1 + 1e-9f);
    float4 sc1 = *(const float4*)(scale + 128 + c4);
    float4 of1 = *(const float4*)(offset + 128 + c4);
    float ns0 = e0 * sc1.x * r1 + of1.x;
    float ns1 = e1 * sc1.y * r1 + of1.y;
    float ns2 = e2 * sc1.z * r1 + of1.z;
    float ns3 = e3 * sc1.w * r1 + of1.w;

    float4 o;
    o.x = 0.5f * (ns0 + nn0);
    o.y = 0.5f * (ns1 + nn1);
    o.z = 0.5f * (ns2 + nn2);
    o.w = 0.5f * (ns3 + nn3);
    *(float4*)(out + (size_t)nid * DOUT + c4) = o;
}

extern "C" void kernel_launch(void* const* d_in, const int* in_sizes, int n_in,
                              void* d_out, int out_size, void* d_ws, size_t ws_size,
                              hipStream_t stream) {
    const float* feat  = (const float*)d_in[0];
    const int*   erow  = (const int*)  d_in[1];
    const int*   ecol  = (const int*)  d_in[2];
    const float* eval  = (const float*)d_in[3];
    const float* W0    = (const float*)d_in[4];
    const float* b0    = (const float*)d_in[5];
    const float* W1    = (const float*)d_in[6];
    const float* b1    = (const float*)d_in[7];
    const float* att   = (const float*)d_in[8];
    const float* scale = (const float*)d_in[9];
    const float* offs  = (const float*)d_in[10];
    const int n = in_sizes[0] / DIN;
    const int E = in_sizes[2];

    float*          h_self    = (float*)d_ws;
    unsigned short* h_neigh   = (unsigned short*)(h_self + (size_t)n * DOUT);
    float*          att_self  = (float*)(h_neigh + (size_t)n * DOUT);
    float*          att_neigh = att_self  + (size_t)n * NHEAD;
    float*          wbuf      = att_neigh + (size_t)n * NHEAD;
    int*            rowptr    = (int*)(wbuf + (size_t)E * NHEAD);

    k1_mfma<<<(n + NPB - 1) / NPB, 256, 0, stream>>>(
        feat, W0, b0, W1, b1, att, h_self, h_neigh, att_self, att_neigh, n);
    k2_rowptr<<<(n + 1 + 255) / 256, 256, 0, stream>>>(erow, rowptr, n, E);
    k_edgew<<<(E + 255) / 256, 256, 0, stream>>>(erow, ecol, eval,
                                                 att_self, att_neigh, wbuf, E);
    k3_agg<<<(n + 7) / 8, 256, 0, stream>>>(rowptr, ecol, wbuf, h_self, h_neigh,
                                            scale, offs, (float*)d_out, n);
}

// Round 4
// 154.843 us; speedup vs baseline: 3.3013x; 1.0859x over previous
//
#include <hip/hip_runtime.h>
#include <hip/hip_bf16.h>

#define NHEAD 4
#define DIN 128
#define DOUT 128

typedef __attribute__((ext_vector_type(8))) short bf16x8;
typedef __attribute__((ext_vector_type(4))) float f32x4;

__device__ __forceinline__ short bfb(float f) {
    __hip_bfloat16 h = __float2bfloat16(f);
    return *reinterpret_cast<short*>(&h);
}

__device__ __forceinline__ float bf2f(unsigned short u) {
    unsigned int x = ((unsigned int)u) << 16;
    return __uint_as_float(x);
}

__device__ __forceinline__ bf16x8 cvt8(const float* __restrict__ p) {
    float4 u = *(const float4*)p;
    float4 v = *(const float4*)(p + 4);
    bf16x8 r;
    r[0] = bfb(u.x); r[1] = bfb(u.y); r[2] = bfb(u.z); r[3] = bfb(u.w);
    r[4] = bfb(v.x); r[5] = bfb(v.y); r[6] = bfb(v.z); r[7] = bfb(v.w);
    return r;
}

// ---------------- K1: MFMA dual projection + ReLU + attention logits ----------------
// 256 threads = 4 independent waves (no LDS, no barriers). Wave w owns channels
// [w*64, w*64+64): w<2 -> h_self, w>=2 -> h_neigh (both stored bf16).
// Attention logit per head reduced in 16 lanes, stored directly by col==0 lanes.
#define NPB 64   // nodes per block (4 tiles)

__global__ __launch_bounds__(256) void k1_mfma(
    const float* __restrict__ feat, const float* __restrict__ W0,
    const float* __restrict__ b0, const float* __restrict__ W1,
    const float* __restrict__ b1, const float* __restrict__ att,
    unsigned short* __restrict__ h_self, unsigned short* __restrict__ h_neigh,
    float* __restrict__ att_self, float* __restrict__ att_neigh,
    int n)
{
    const int t = threadIdx.x;
    const int w = t >> 6;          // wave 0..3
    const int lane = t & 63;
    const int col = lane & 15;     // channel-within-16 (and A row index)
    const int rg = lane >> 4;      // k-group / row-group

    // preload B fragments (weights) for this wave's 64 channels, bf16 in regs
    bf16x8 bw[4][4];
    float bias[4], aw[4];
    #pragma unroll
    for (int ct = 0; ct < 4; ct++) {
        int ch = w * 64 + ct * 16 + col;          // global channel 0..255
        int chm = ch & 127;
        const float* wrow = (ch < 128 ? W0 : W1) + (size_t)chm * DIN;
        #pragma unroll
        for (int kk = 0; kk < 4; kk++)
            bw[ct][kk] = cvt8(wrow + kk * 32 + rg * 8);
        bias[ct] = (ch < 128 ? b0 : b1)[chm];
        aw[ct]   = att[ch];
    }
    unsigned short* const hout = (w < 2) ? h_self : h_neigh;
    float* const aout = (w < 2) ? att_self : att_neigh;
    const int hbase = (w & 1) * 2;   // first of the 2 heads this wave reduces

    const int ntiles = (n + 15) >> 4;
    const int tile0 = blockIdx.x * (NPB / 16);
    const int tile1 = min(tile0 + NPB / 16, ntiles);

    for (int tile = tile0; tile < tile1; tile++) {
        const int base = tile * 16;
        const int anode = base + col;
        const bool avalid = anode < n;
        const float* arow = feat + (size_t)anode * DIN + rg * 8;

        bf16x8 a[4];
        if (avalid) {
            #pragma unroll
            for (int kk = 0; kk < 4; kk++) a[kk] = cvt8(arow + kk * 32);
        } else {
            #pragma unroll
            for (int kk = 0; kk < 4; kk++) {
                #pragma unroll
                for (int i = 0; i < 8; i++) a[kk][i] = 0;
            }
        }

        f32x4 acc[4] = {{0.f,0.f,0.f,0.f},{0.f,0.f,0.f,0.f},
                        {0.f,0.f,0.f,0.f},{0.f,0.f,0.f,0.f}};
        #pragma unroll
        for (int kk = 0; kk < 4; kk++) {
            #pragma unroll
            for (int ct = 0; ct < 4; ct++)
                acc[ct] = __builtin_amdgcn_mfma_f32_16x16x32_bf16(
                              a[kk], bw[ct][kk], acc[ct], 0, 0, 0);
        }

        // epilogue: bias + ReLU + store h (bf16); attention logits via shuffles
        float vv[4][4];
        #pragma unroll
        for (int ct = 0; ct < 4; ct++) {
            #pragma unroll
            for (int j = 0; j < 4; j++) {
                float v = acc[ct][j] + bias[ct];
                v = v > 0.f ? v : 0.f;
                vv[ct][j] = v;
                int node = base + rg * 4 + j;
                int chm = (w * 64 + ct * 16 + col) & 127;
                if (node < n)
                    hout[(size_t)node * DOUT + chm] = (unsigned short)bfb(v);
            }
        }
        #pragma unroll
        for (int j = 0; j < 4; j++) {
            float p0 = vv[0][j] * aw[0] + vv[1][j] * aw[1];   // head hbase
            float p1 = vv[2][j] * aw[2] + vv[3][j] * aw[3];   // head hbase+1
            #pragma unroll
            for (int m = 1; m < 16; m <<= 1) {
                p0 += __shfl_xor(p0, m);
                p1 += __shfl_xor(p1, m);
            }
            if (col == 0) {
                int node = base + rg * 4 + j;
                if (node < n) {
                    float2 o;
                    o.x = p0 > 0.f ? p0 : 0.2f * p0;          // leaky relu
                    o.y = p1 > 0.f ? p1 : 0.2f * p1;
                    *(float2*)(aout + (size_t)node * NHEAD + hbase) = o;
                }
            }
        }
    }
}

// ---------------- K2: CSR offsets by binary search on sorted edge_row ----------------
__global__ void k2_rowptr(const int* __restrict__ erow, int* __restrict__ rowptr,
                          int n_nodes, int nedge)
{
    int n = blockIdx.x * blockDim.x + threadIdx.x;
    if (n > n_nodes) return;
    int lo = 0, hi = nedge;
    while (lo < hi) { int mid = (lo + hi) >> 1; if (erow[mid] < n) lo = mid + 1; else hi = mid; }
    rowptr[n] = lo;
}

// ---------------- K3: fused edge softmax + weighted aggregate + dual layernorm ------
// 256 threads = 8 nodes/block, 32 lanes/node, 4 channels/thread.
// Per-edge weight exp(as+an)*eval computed inline (no wbuf). Batches of 4 with
// col prefetch; invalid slots get ev=0 and re-gather the current col (free line).
__device__ __forceinline__ float group8_sum(float v) {
    v += __shfl_xor(v, 1);
    v += __shfl_xor(v, 2);
    v += __shfl_xor(v, 4);
    return v;
}

__global__ __launch_bounds__(256) void k3_agg(
    const int* __restrict__ rowptr, const int* __restrict__ ecol,
    const float* __restrict__ eval,
    const float* __restrict__ att_self, const float* __restrict__ att_neigh,
    const unsigned short* __restrict__ h_self, const unsigned short* __restrict__ h_neigh,
    const float* __restrict__ scale, const float* __restrict__ offset,
    float* __restrict__ out, int n_nodes)
{
    const int t = threadIdx.x;
    const int g = t >> 5;
    const int lane = t & 31;
    const int nid = blockIdx.x * 8 + g;
    if (nid >= n_nodes) return;
    const int h = lane >> 3;                    // head
    const int c4 = lane * 4;                    // first of 4 owned channels

    const int start = rowptr[nid], end = rowptr[nid + 1];
    const float as = att_self[(size_t)nid * NHEAD + h];

    float acc0 = 0.f, acc1 = 0.f, acc2 = 0.f, acc3 = 0.f, sumw = 0.f;

    int cols[4];
    #pragma unroll
    for (int i = 0; i < 4; i++)
        cols[i] = (start + i < end) ? ecol[start + i]
                                    : (start < end ? ecol[start] : 0);

    for (int e = start; e < end; e += 4) {
        float ev[4], an[4];
        ushort4 hv[4];
        #pragma unroll
        for (int i = 0; i < 4; i++) {
            ev[i] = (e + i < end) ? eval[e + i] : 0.f;
            an[i] = att_neigh[(size_t)cols[i] * NHEAD + h];
            hv[i] = *(const ushort4*)(h_neigh + (size_t)cols[i] * DOUT + c4);
        }
        int ncols[4];
        #pragma unroll
        for (int i = 0; i < 4; i++) {
            int en = e + 4 + i;
            ncols[i] = (en < end) ? ecol[en] : cols[i];
        }
        #pragma unroll
        for (int i = 0; i < 4; i++) {
            float wh = __expf(as + an[i]) * ev[i];
            sumw += wh;
            acc0 = fmaf(wh, bf2f(hv[i].x), acc0);
            acc1 = fmaf(wh, bf2f(hv[i].y), acc1);
            acc2 = fmaf(wh, bf2f(hv[i].z), acc2);
            acc3 = fmaf(wh, bf2f(hv[i].w), acc3);
        }
        #pragma unroll
        for (int i = 0; i < 4; i++) cols[i] = ncols[i];
    }

    const float rden = 1.f / fmaxf(sumw, 1e-10f);
    float a0 = acc0 * rden, a1 = acc1 * rden, a2 = acc2 * rden, a3 = acc3 * rden;

    // layernorm of agg over this head's 32 channels (8 lanes x 4)
    float m0 = group8_sum(a0 + a1 + a2 + a3) * (1.f / 32.f);
    float d0 = a0 - m0, d1 = a1 - m0, d2 = a2 - m0, d3 = a3 - m0;
    float v0 = group8_sum(d0*d0 + d1*d1 + d2*d2 + d3*d3) * (1.f / 32.f);
    float r0 = rsqrtf(v0 + 1e-9f);
    float4 sc0 = *(const float4*)(scale + c4);
    float4 of0 = *(const float4*)(offset + c4);
    float nn0 = d0 * sc0.x * r0 + of0.x;
    float nn1 = d1 * sc0.y * r0 + of0.y;
    float nn2 = d2 * sc0.z * r0 + of0.z;
    float nn3 = d3 * sc0.w * r0 + of0.w;

    // layernorm of h_self (bf16)
    ushort4 hsu = *(const ushort4*)(h_self + (size_t)nid * DOUT + c4);
    float h0 = bf2f(hsu.x), h1 = bf2f(hsu.y), h2 = bf2f(hsu.z), h3 = bf2f(hsu.w);
    float m1 = group8_sum(h0 + h1 + h2 + h3) * (1.f / 32.f);
    float e0 = h0 - m1, e1 = h1 - m1, e2 = h2 - m1, e3 = h3 - m1;
    float v1 = group8_sum(e0*e0 + e1*e1 + e2*e2 + e3*e3) * (1.f / 32.f);
    float r1 = rsqrtf(v1 + 1e-9f);
    float4 sc1 = *(const float4*)(scale + 128 + c4);
    float4 of1 = *(const float4*)(offset + 128 + c4);
    float ns0 = e0 * sc1.x * r1 + of1.x;
    float ns1 = e1 * sc1.y * r1 + of1.y;
    float ns2 = e2 * sc1.z * r1 + of1.z;
    float ns3 = e3 * sc1.w * r1 + of1.w;

    float4 o;
    o.x = 0.5f * (ns0 + nn0);
    o.y = 0.5f * (ns1 + nn1);
    o.z = 0.5f * (ns2 + nn2);
    o.w = 0.5f * (ns3 + nn3);
    *(float4*)(out + (size_t)nid * DOUT + c4) = o;
}

extern "C" void kernel_launch(void* const* d_in, const int* in_sizes, int n_in,
                              void* d_out, int out_size, void* d_ws, size_t ws_size,
                              hipStream_t stream) {
    const float* feat  = (const float*)d_in[0];
    const int*   erow  = (const int*)  d_in[1];
    const int*   ecol  = (const int*)  d_in[2];
    const float* eval  = (const float*)d_in[3];
    const float* W0    = (const float*)d_in[4];
    const float* b0    = (const float*)d_in[5];
    const float* W1    = (const float*)d_in[6];
    const float* b1    = (const float*)d_in[7];
    const float* att   = (const float*)d_in[8];
    const float* scale = (const float*)d_in[9];
    const float* offs  = (const float*)d_in[10];
    const int n = in_sizes[0] / DIN;
    const int E = in_sizes[2];

    unsigned short* h_self    = (unsigned short*)d_ws;
    unsigned short* h_neigh   = h_self + (size_t)n * DOUT;
    float*          att_self  = (float*)(h_neigh + (size_t)n * DOUT);
    float*          att_neigh = att_self  + (size_t)n * NHEAD;
    int*            rowptr    = (int*)(att_neigh + (size_t)n * NHEAD);

    k1_mfma<<<(n + NPB - 1) / NPB, 256, 0, stream>>>(
        feat, W0, b0, W1, b1, att, h_self, h_neigh, att_self, att_neigh, n);
    k2_rowptr<<<(n + 1 + 255) / 256, 256, 0, stream>>>(erow, rowptr, n, E);
    k3_agg<<<(n + 7) / 8, 256, 0, stream>>>(rowptr, ecol, eval, att_self, att_neigh,
                                            h_self, h_neigh, scale, offs,
                                            (float*)d_out, n);
}

// Round 5
// 150.740 us; speedup vs baseline: 3.3911x; 1.0272x over previous
//
#include <hip/hip_runtime.h>
#include <hip/hip_bf16.h>

#define NHEAD 4
#define DIN 128
#define DOUT 128

typedef __attribute__((ext_vector_type(8))) short bf16x8;
typedef __attribute__((ext_vector_type(4))) float f32x4;

__device__ __forceinline__ short bfb(float f) {
    __hip_bfloat16 h = __float2bfloat16(f);
    return *reinterpret_cast<short*>(&h);
}

__device__ __forceinline__ float2 bfpair(unsigned int u) {
    float2 r;
    r.x = __uint_as_float(u << 16);
    r.y = __uint_as_float(u & 0xFFFF0000u);
    return r;
}

__device__ __forceinline__ bf16x8 cvt8(const float* __restrict__ p) {
    float4 u = *(const float4*)p;
    float4 v = *(const float4*)(p + 4);
    bf16x8 r;
    r[0] = bfb(u.x); r[1] = bfb(u.y); r[2] = bfb(u.z); r[3] = bfb(u.w);
    r[4] = bfb(v.x); r[5] = bfb(v.y); r[6] = bfb(v.z); r[7] = bfb(v.w);
    return r;
}

// ---------------- K1: MFMA dual projection + ReLU + attention logits ----------------
// Operands SWAPPED vs R4: A = weights (channels = D rows), B = feat (nodes = D cols).
// Lane owns 4 consecutive channels of node (lane&15) -> one ushort4 store per ct.
// 4 independent waves, no LDS, no barriers.
#define NPB 64   // nodes per block (4 tiles)

__global__ __launch_bounds__(256) void k1_mfma(
    const float* __restrict__ feat, const float* __restrict__ W0,
    const float* __restrict__ b0, const float* __restrict__ W1,
    const float* __restrict__ b1, const float* __restrict__ att,
    unsigned short* __restrict__ h_self, unsigned short* __restrict__ h_neigh,
    float* __restrict__ att_self, float* __restrict__ att_neigh,
    int n)
{
    const int t = threadIdx.x;
    const int w = t >> 6;          // wave 0..3: channels [w*64, w*64+64)
    const int lane = t & 63;
    const int col = lane & 15;     // node index within tile (D col); W row for A-frags
    const int rg = lane >> 4;      // k-group for loads; D row group for epilogue

    // A-operand: weight fragments for this wave's 64 channels (bf16, in regs)
    bf16x8 bw[4][4];
    #pragma unroll
    for (int ct = 0; ct < 4; ct++) {
        int ch = w * 64 + ct * 16 + col;          // A-row mapping: lane&15
        int chm = ch & 127;
        const float* wrow = (ch < 128 ? W0 : W1) + (size_t)chm * DIN;
        #pragma unroll
        for (int kk = 0; kk < 4; kk++)
            bw[ct][kk] = cvt8(wrow + kk * 32 + rg * 8);
    }
    // epilogue params use the D-row mapping: ch = w*64 + ct*16 + rg*4 + j
    float4 bias4[4], att4[4];
    #pragma unroll
    for (int ct = 0; ct < 4; ct++) {
        int ch = w * 64 + ct * 16 + rg * 4;
        int chm = ch & 127;
        bias4[ct] = *(const float4*)((ch < 128 ? b0 : b1) + chm);
        att4[ct]  = *(const float4*)(att + ch);
    }
    unsigned short* const hout = (w < 2) ? h_self : h_neigh;
    float* const aout = (w < 2) ? att_self : att_neigh;
    const int hbase = (w & 1) * 2;   // first of 2 heads this wave covers

    const int ntiles = (n + 15) >> 4;
    const int tile0 = blockIdx.x * (NPB / 16);
    const int tile1 = min(tile0 + NPB / 16, ntiles);

    for (int tile = tile0; tile < tile1; tile++) {
        const int base = tile * 16;
        const int node = base + col;             // B col / D col
        const bool valid = node < n;
        const float* frow = feat + (size_t)node * DIN + rg * 8;

        bf16x8 b[4];
        if (valid) {
            #pragma unroll
            for (int kk = 0; kk < 4; kk++) b[kk] = cvt8(frow + kk * 32);
        } else {
            #pragma unroll
            for (int kk = 0; kk < 4; kk++) {
                #pragma unroll
                for (int i = 0; i < 8; i++) b[kk][i] = 0;
            }
        }

        f32x4 acc[4] = {{0.f,0.f,0.f,0.f},{0.f,0.f,0.f,0.f},
                        {0.f,0.f,0.f,0.f},{0.f,0.f,0.f,0.f}};
        #pragma unroll
        for (int kk = 0; kk < 4; kk++) {
            #pragma unroll
            for (int ct = 0; ct < 4; ct++)
                acc[ct] = __builtin_amdgcn_mfma_f32_16x16x32_bf16(
                              bw[ct][kk], b[kk], acc[ct], 0, 0, 0);
        }

        // epilogue: bias + ReLU, pack 4 consecutive channels -> ushort4 store
        float p0 = 0.f, p1 = 0.f;
        #pragma unroll
        for (int ct = 0; ct < 4; ct++) {
            float4 bi = bias4[ct], aa = att4[ct];
            float v0 = fmaxf(acc[ct][0] + bi.x, 0.f);
            float v1 = fmaxf(acc[ct][1] + bi.y, 0.f);
            float v2 = fmaxf(acc[ct][2] + bi.z, 0.f);
            float v3 = fmaxf(acc[ct][3] + bi.w, 0.f);
            ushort4 st;
            st.x = (unsigned short)bfb(v0);
            st.y = (unsigned short)bfb(v1);
            st.z = (unsigned short)bfb(v2);
            st.w = (unsigned short)bfb(v3);
            int choff = (w * 64 + ct * 16 + rg * 4) & 127;
            if (valid)
                *(ushort4*)(hout + (size_t)node * DOUT + choff) = st;
            float pp = v0 * aa.x + v1 * aa.y + v2 * aa.z + v3 * aa.w;
            if (ct < 2) p0 += pp; else p1 += pp;
        }
        // reduce attention partials across the 4 rg groups
        p0 += __shfl_xor(p0, 16); p0 += __shfl_xor(p0, 32);
        p1 += __shfl_xor(p1, 16); p1 += __shfl_xor(p1, 32);
        if (rg == 0 && valid) {
            float2 o;
            o.x = p0 > 0.f ? p0 : 0.2f * p0;
            o.y = p1 > 0.f ? p1 : 0.2f * p1;
            *(float2*)(aout + (size_t)node * NHEAD + hbase) = o;
        }
    }
}

// ---------------- K2: CSR offsets by binary search on sorted edge_row ----------------
__global__ void k2_rowptr(const int* __restrict__ erow, int* __restrict__ rowptr,
                          int n_nodes, int nedge)
{
    int n = blockIdx.x * blockDim.x + threadIdx.x;
    if (n > n_nodes) return;
    int lo = 0, hi = nedge;
    while (lo < hi) { int mid = (lo + hi) >> 1; if (erow[mid] < n) lo = mid + 1; else hi = mid; }
    rowptr[n] = lo;
}

// ---------------- K3: fused edge softmax + weighted aggregate + dual layernorm ------
// 256 threads = 16 nodes/block, 16 lanes/node, 8 channels/thread (uint4 = b128 gather).
// Explicit 2-stage pipeline: next batch's (hv, an, ev) loads issued before current
// batch is consumed; next-next cols prefetched.
__device__ __forceinline__ float group4_sum(float v) {
    v += __shfl_xor(v, 1);
    v += __shfl_xor(v, 2);
    return v;
}

__global__ __launch_bounds__(256) void k3_agg(
    const int* __restrict__ rowptr, const int* __restrict__ ecol,
    const float* __restrict__ eval,
    const float* __restrict__ att_self, const float* __restrict__ att_neigh,
    const unsigned short* __restrict__ h_self, const unsigned short* __restrict__ h_neigh,
    const float* __restrict__ scale, const float* __restrict__ offset,
    float* __restrict__ out, int n_nodes)
{
    const int t = threadIdx.x;
    const int g = t >> 4;                       // node slot 0..15
    const int lane = t & 15;
    const int nid = blockIdx.x * 16 + g;
    if (nid >= n_nodes) return;
    const int head = lane >> 2;
    const int c8 = lane * 8;                    // first of 8 owned channels

    const int start = rowptr[nid], end = rowptr[nid + 1];
    const float as = att_self[(size_t)nid * NHEAD + head];

    float acc[8];
    #pragma unroll
    for (int j = 0; j < 8; j++) acc[j] = 0.f;
    float sumw = 0.f;

    int colsC[4], colsN[4];
    #pragma unroll
    for (int i = 0; i < 4; i++)
        colsC[i] = (start + i < end) ? ecol[start + i] : 0;
    #pragma unroll
    for (int i = 0; i < 4; i++)
        colsN[i] = (start + 4 + i < end) ? ecol[start + 4 + i] : 0;

    uint4 hvC[4]; float evC[4], anC[4];
    #pragma unroll
    for (int i = 0; i < 4; i++) {
        evC[i] = (start + i < end) ? eval[start + i] : 0.f;
        anC[i] = att_neigh[(size_t)colsC[i] * NHEAD + head];
        hvC[i] = *(const uint4*)(h_neigh + (size_t)colsC[i] * DOUT + c8);
    }

    for (int e = start; e < end; e += 4) {
        const int e2 = e + 4;
        // issue next batch's loads (independent of current batch's consumption)
        uint4 hvN[4]; float evN[4], anN[4];
        #pragma unroll
        for (int i = 0; i < 4; i++) {
            evN[i] = (e2 + i < end) ? eval[e2 + i] : 0.f;
            anN[i] = att_neigh[(size_t)colsN[i] * NHEAD + head];
            hvN[i] = *(const uint4*)(h_neigh + (size_t)colsN[i] * DOUT + c8);
        }
        int colsNN[4];
        #pragma unroll
        for (int i = 0; i < 4; i++)
            colsNN[i] = (e + 8 + i < end) ? ecol[e + 8 + i] : 0;

        // consume current batch
        #pragma unroll
        for (int i = 0; i < 4; i++) {
            float wh = __expf(as + anC[i]) * evC[i];
            sumw += wh;
            float2 p;
            p = bfpair(hvC[i].x); acc[0] = fmaf(wh, p.x, acc[0]); acc[1] = fmaf(wh, p.y, acc[1]);
            p = bfpair(hvC[i].y); acc[2] = fmaf(wh, p.x, acc[2]); acc[3] = fmaf(wh, p.y, acc[3]);
            p = bfpair(hvC[i].z); acc[4] = fmaf(wh, p.x, acc[4]); acc[5] = fmaf(wh, p.y, acc[5]);
            p = bfpair(hvC[i].w); acc[6] = fmaf(wh, p.x, acc[6]); acc[7] = fmaf(wh, p.y, acc[7]);
        }
        // shift pipeline
        #pragma unroll
        for (int i = 0; i < 4; i++) {
            hvC[i] = hvN[i]; evC[i] = evN[i]; anC[i] = anN[i]; colsN[i] = colsNN[i];
        }
    }

    const float rden = 1.f / fmaxf(sumw, 1e-10f);
    float a[8];
    #pragma unroll
    for (int j = 0; j < 8; j++) a[j] = acc[j] * rden;

    // layernorm of agg over this head's 32 channels (4 lanes x 8)
    float s0 = 0.f;
    #pragma unroll
    for (int j = 0; j < 8; j++) s0 += a[j];
    float m0 = group4_sum(s0) * (1.f / 32.f);
    float q0 = 0.f;
    float d[8];
    #pragma unroll
    for (int j = 0; j < 8; j++) { d[j] = a[j] - m0; q0 += d[j] * d[j]; }
    float r0 = rsqrtf(group4_sum(q0) * (1.f / 32.f) + 1e-9f);
    float4 sc0a = *(const float4*)(scale + c8);
    float4 sc0b = *(const float4*)(scale + c8 + 4);
    float4 of0a = *(const float4*)(offset + c8);
    float4 of0b = *(const float4*)(offset + c8 + 4);
    const float sc0[8] = {sc0a.x, sc0a.y, sc0a.z, sc0a.w, sc0b.x, sc0b.y, sc0b.z, sc0b.w};
    const float of0[8] = {of0a.x, of0a.y, of0a.z, of0a.w, of0b.x, of0b.y, of0b.z, of0b.w};

    // layernorm of h_self (bf16)
    uint4 hsu = *(const uint4*)(h_self + (size_t)nid * DOUT + c8);
    float hs[8];
    { float2 p;
      p = bfpair(hsu.x); hs[0] = p.x; hs[1] = p.y;
      p = bfpair(hsu.y); hs[2] = p.x; hs[3] = p.y;
      p = bfpair(hsu.z); hs[4] = p.x; hs[5] = p.y;
      p = bfpair(hsu.w); hs[6] = p.x; hs[7] = p.y; }
    float s1 = 0.f;
    #pragma unroll
    for (int j = 0; j < 8; j++) s1 += hs[j];
    float m1 = group4_sum(s1) * (1.f / 32.f);
    float q1 = 0.f;
    float eh[8];
    #pragma unroll
    for (int j = 0; j < 8; j++) { eh[j] = hs[j] - m1; q1 += eh[j] * eh[j]; }
    float r1 = rsqrtf(group4_sum(q1) * (1.f / 32.f) + 1e-9f);
    float4 sc1a = *(const float4*)(scale + 128 + c8);
    float4 sc1b = *(const float4*)(scale + 128 + c8 + 4);
    float4 of1a = *(const float4*)(offset + 128 + c8);
    float4 of1b = *(const float4*)(offset + 128 + c8 + 4);
    const float sc1[8] = {sc1a.x, sc1a.y, sc1a.z, sc1a.w, sc1b.x, sc1b.y, sc1b.z, sc1b.w};
    const float of1[8] = {of1a.x, of1a.y, of1a.z, of1a.w, of1b.x, of1b.y, of1b.z, of1b.w};

    float o[8];
    #pragma unroll
    for (int j = 0; j < 8; j++) {
        float nn = d[j]  * sc0[j] * r0 + of0[j];
        float ns = eh[j] * sc1[j] * r1 + of1[j];
        o[j] = 0.5f * (ns + nn);
    }
    float4 oa = make_float4(o[0], o[1], o[2], o[3]);
    float4 ob = make_float4(o[4], o[5], o[6], o[7]);
    *(float4*)(out + (size_t)nid * DOUT + c8)     = oa;
    *(float4*)(out + (size_t)nid * DOUT + c8 + 4) = ob;
}

extern "C" void kernel_launch(void* const* d_in, const int* in_sizes, int n_in,
                              void* d_out, int out_size, void* d_ws, size_t ws_size,
                              hipStream_t stream) {
    const float* feat  = (const float*)d_in[0];
    const int*   erow  = (const int*)  d_in[1];
    const int*   ecol  = (const int*)  d_in[2];
    const float* eval  = (const float*)d_in[3];
    const float* W0    = (const float*)d_in[4];
    const float* b0    = (const float*)d_in[5];
    const float* W1    = (const float*)d_in[6];
    const float* b1    = (const float*)d_in[7];
    const float* att   = (const float*)d_in[8];
    const float* scale = (const float*)d_in[9];
    const float* offs  = (const float*)d_in[10];
    const int n = in_sizes[0] / DIN;
    const int E = in_sizes[2];

    unsigned short* h_self    = (unsigned short*)d_ws;
    unsigned short* h_neigh   = h_self + (size_t)n * DOUT;
    float*          att_self  = (float*)(h_neigh + (size_t)n * DOUT);
    float*          att_neigh = att_self  + (size_t)n * NHEAD;
    int*            rowptr    = (int*)(att_neigh + (size_t)n * NHEAD);

    k1_mfma<<<(n + NPB - 1) / NPB, 256, 0, stream>>>(
        feat, W0, b0, W1, b1, att, h_self, h_neigh, att_self, att_neigh, n);
    k2_rowptr<<<(n + 1 + 255) / 256, 256, 0, stream>>>(erow, rowptr, n, E);
    k3_agg<<<(n + 15) / 16, 256, 0, stream>>>(rowptr, ecol, eval, att_self, att_neigh,
                                              h_self, h_neigh, scale, offs,
                                              (float*)d_out, n);
}